// Round 9
// baseline (357.142 us; speedup 1.0000x reference)
//
#include <hip/hip_runtime.h>
#include <hip/hip_bf16.h>

#define N_NODES 50000
#define N_EDGES 1600000
#define ET (N_EDGES + N_NODES)   // self-loops appended
#define IN_DIM 256
#define HID 128
#define NCLS 40
#define NEG 0.2f
#define NBUCK 391                // ceil(50000 / 128) buckets of 128 dst nodes
#define CHUNK 4096               // edges per binning workgroup
#define R1D (N_NODES * 20 + 16)  // h1 replica stride in dwords (64B-aligned)

typedef short bf16x8 __attribute__((ext_vector_type(8)));
typedef float f32x4  __attribute__((ext_vector_type(4)));

__device__ __forceinline__ unsigned pk2(float a, float b) {
    __hip_bfloat16 ha = __float2bfloat16(a), hb = __float2bfloat16(b);
    unsigned short ua = *(unsigned short*)&ha, ub = *(unsigned short*)&hb;
    return (unsigned)ua | ((unsigned)ub << 16);
}
__device__ __forceinline__ float blo(unsigned u) { return __uint_as_float(u << 16); }
__device__ __forceinline__ float bhi(unsigned u) { return __uint_as_float(u & 0xffff0000u); }

// ---------------- CSR build: two-level binning (no per-edge global atomics) ----
__global__ __launch_bounds__(256) void k_bin_count(const int* __restrict__ ei,
                                                   int* __restrict__ bcnt) {
    __shared__ int hist[NBUCK];
    int t = threadIdx.x;
    for (int i = t; i < NBUCK; i += 256) hist[i] = 0;
    __syncthreads();
    int base = blockIdx.x * CHUNK;
    #pragma unroll
    for (int j = 0; j < 16; ++j) {
        int i = base + j * 256 + t;
        if (i < ET) {
            int d = (i < N_EDGES) ? ei[N_EDGES + i] : (i - N_EDGES);
            atomicAdd(&hist[d >> 7], 1);
        }
    }
    __syncthreads();
    for (int i = t; i < NBUCK; i += 256) if (hist[i]) atomicAdd(&bcnt[i], hist[i]);
}

__global__ __launch_bounds__(512) void k_bin_scan(const int* __restrict__ bcnt,
                                                  int* __restrict__ cstart,
                                                  int* __restrict__ cursor,
                                                  int* __restrict__ rp) {
    __shared__ int s[512];
    int t = threadIdx.x;
    int v = (t < NBUCK) ? bcnt[t] : 0;
    s[t] = v;
    __syncthreads();
    for (int off = 1; off < 512; off <<= 1) {
        int u = (t >= off) ? s[t - off] : 0;
        __syncthreads();
        s[t] += u;
        __syncthreads();
    }
    int ex = s[t] - v;   // exclusive prefix
    if (t < NBUCK) { cstart[t] = ex; cursor[t] = ex; }
    if (t == 0) { cstart[NBUCK] = ET; rp[N_NODES] = ET; }
}

__global__ __launch_bounds__(256) void k_bin_scatter(const int* __restrict__ ei,
                                                     int* __restrict__ cursor,
                                                     unsigned int* __restrict__ buf) {
    __shared__ int sd[CHUNK];     // staged dst (or -1 past end)
    __shared__ int hist[NBUCK];
    __shared__ int wbase[NBUCK];
    int t = threadIdx.x;
    for (int i = t; i < NBUCK; i += 256) hist[i] = 0;
    __syncthreads();
    int base = blockIdx.x * CHUNK;
    #pragma unroll
    for (int j = 0; j < 16; ++j) {
        int i = base + j * 256 + t;
        int d = -1;
        if (i < ET) d = (i < N_EDGES) ? ei[N_EDGES + i] : (i - N_EDGES);
        sd[j * 256 + t] = d;
        if (d >= 0) atomicAdd(&hist[d >> 7], 1);
    }
    __syncthreads();
    for (int i = t; i < NBUCK; i += 256) {
        int h = hist[i];
        wbase[i] = h ? atomicAdd(&cursor[i], h) : 0;
        hist[i] = 0;              // reuse as running offset
    }
    __syncthreads();
    #pragma unroll
    for (int j = 0; j < 16; ++j) {
        int i = base + j * 256 + t;
        int d = sd[j * 256 + t];
        if (d >= 0) {
            int s_ = (i < N_EDGES) ? ei[i] : d;
            int b = d >> 7;
            int off = atomicAdd(&hist[b], 1);
            buf[wbase[b] + off] = ((unsigned)(d & 127) << 16) | (unsigned)s_;
        }
    }
}

__global__ __launch_bounds__(256) void k_bucket_build(const unsigned int* __restrict__ buf,
                                                      const int* __restrict__ cstart,
                                                      int* __restrict__ rp,
                                                      int* __restrict__ csr) {
    __shared__ int cnt[128], rpl[128], cur[128];
    int b = blockIdx.x;
    int t = threadIdx.x;
    int lo = cstart[b], hi = cstart[b + 1];
    if (t < 128) cnt[t] = 0;
    __syncthreads();
    for (int i = lo + t; i < hi; i += 256) atomicAdd(&cnt[buf[i] >> 16], 1);
    __syncthreads();
    if (t == 0) {
        int run = 0;
        #pragma unroll
        for (int l = 0; l < 128; ++l) { rpl[l] = run; run += cnt[l]; }
    }
    __syncthreads();
    if (t < 128) {
        int node = b * 128 + t;
        if (node < N_NODES) rp[node] = lo + rpl[t];
        cur[t] = 0;
    }
    __syncthreads();
    for (int i = lo + t; i < hi; i += 256) {
        unsigned v = buf[i];
        int dl = v >> 16;
        int off = atomicAdd(&cur[dl], 1);
        csr[lo + rpl[dl] + off] = (int)(v & 0xffffu);
    }
}

// ---------------- Edge weights: wn[e] = softmax weight (normalized), fp32 ------
__global__ __launch_bounds__(256) void k_wts(
    const float* __restrict__ as, const float* __restrict__ ad,
    const int* __restrict__ rp, const int* __restrict__ csr,
    float* __restrict__ wn) {
    int wid = threadIdx.x >> 6, lane = threadIdx.x & 63;
    int node = blockIdx.x * 4 + wid;
    int start = rp[node], end = rp[node + 1];
    float ad_n = ad[node];
    float den = 0.f;
    for (int base = start; base < end; base += 64) {
        int mm = end - base; if (mm > 64) mm = 64;
        if (lane < mm) {
            int s = csr[base + lane];
            float e = as[s] + ad_n;
            e = (e > 0.f) ? e : NEG * e;
            float w = __expf(e);
            den += w;
            wn[base + lane] = w;
        }
    }
    #pragma unroll
    for (int off = 32; off; off >>= 1) den += __shfl_xor(den, off);
    float inv = 1.f / fmaxf(den, 1e-16f);
    for (int base = start; base < end; base += 64) {
        int mm = end - base; if (mm > 64) mm = 64;
        if (lane < mm) wn[base + lane] *= inv;
    }
}

// ---------------- Layer 0 GEMM (MFMA bf16): h0(bf16) = x @ W0^T + alpha dots ---
__global__ __launch_bounds__(256) void k_gemm0(
    const float* __restrict__ x, const float* __restrict__ W0,
    const float* __restrict__ a_s, const float* __restrict__ a_d,
    unsigned short* __restrict__ h0b, float* __restrict__ as0, float* __restrict__ ad0) {
    __shared__ unsigned sA[64 * 36];    // bf16 [64 rows][72]
    __shared__ unsigned sB[128 * 36];   // bf16 [128 cols][72]
    int t = threadIdx.x;
    int n0 = blockIdx.x * 64;
    int w = t >> 6, lane = t & 63;
    int rw = lane & 15, q = lane >> 4;
    f32x4 acc[8];
    #pragma unroll
    for (int n = 0; n < 8; ++n) acc[n] = (f32x4){0.f, 0.f, 0.f, 0.f};

    for (int kc = 0; kc < IN_DIM; kc += 64) {
        #pragma unroll
        for (int i = 0; i < 4; ++i) {
            int f = i * 256 + t;
            int r = f >> 4, fq = f & 15;
            float4 v = make_float4(0.f, 0.f, 0.f, 0.f);
            if (n0 + r < N_NODES)
                v = *(const float4*)&x[(size_t)(n0 + r) * IN_DIM + kc + fq * 4];
            *(uint2*)&sA[r * 36 + fq * 2] = make_uint2(pk2(v.x, v.y), pk2(v.z, v.w));
        }
        #pragma unroll
        for (int i = 0; i < 8; ++i) {
            int f = i * 256 + t;
            int c = f >> 4, fq = f & 15;
            float4 v = *(const float4*)&W0[(size_t)c * IN_DIM + kc + fq * 4];
            *(uint2*)&sB[c * 36 + fq * 2] = make_uint2(pk2(v.x, v.y), pk2(v.z, v.w));
        }
        __syncthreads();
        #pragma unroll
        for (int ks = 0; ks < 2; ++ks) {
            bf16x8 af = *(const bf16x8*)((const unsigned short*)sA + (16 * w + rw) * 72 + ks * 32 + q * 8);
            #pragma unroll
            for (int n = 0; n < 8; ++n) {
                bf16x8 bfr = *(const bf16x8*)((const unsigned short*)sB + (n * 16 + rw) * 72 + ks * 32 + q * 8);
                acc[n] = __builtin_amdgcn_mfma_f32_16x16x32_bf16(af, bfr, acc[n], 0, 0, 0);
            }
        }
        __syncthreads();
    }

    float asv[8], adv[8];
    #pragma unroll
    for (int n = 0; n < 8; ++n) { asv[n] = a_s[n * 16 + rw]; adv[n] = a_d[n * 16 + rw]; }
    float ps[4] = {0.f, 0.f, 0.f, 0.f}, pd[4] = {0.f, 0.f, 0.f, 0.f};
    #pragma unroll
    for (int n = 0; n < 8; ++n)
        #pragma unroll
        for (int reg = 0; reg < 4; ++reg) {
            float vv = acc[n][reg];
            ps[reg] += vv * asv[n];
            pd[reg] += vv * adv[n];
        }
    #pragma unroll
    for (int reg = 0; reg < 4; ++reg) {
        int node = n0 + 16 * w + q * 4 + reg;
        if (node < N_NODES) {
            #pragma unroll
            for (int n = 0; n < 8; ++n) {
                __hip_bfloat16 hb = __float2bfloat16(acc[n][reg]);
                h0b[(size_t)node * HID + n * 16 + rw] = *(unsigned short*)&hb;
            }
        }
    }
    #pragma unroll
    for (int reg = 0; reg < 4; ++reg)
        #pragma unroll
        for (int off = 1; off < 16; off <<= 1) {
            ps[reg] += __shfl_xor(ps[reg], off);
            pd[reg] += __shfl_xor(pd[reg], off);
        }
    if (rw == 0) {
        #pragma unroll
        for (int reg = 0; reg < 4; ++reg) {
            int node = n0 + 16 * w + q * 4 + reg;
            if (node < N_NODES) { as0[node] = ps[reg]; ad0[node] = pd[reg]; }
        }
    }
}

// ---------------- Aggregation layer 0: 4 column shards (32 cols = 1 line) ------
// shard = blockIdx&3 (round-robin XCD affinity); quarter-wave per edge row.
// h0 row = 128 bf16 = 64 dwords -> gather stride s*64.
__global__ __launch_bounds__(256) void k_agg0(
    const unsigned int* __restrict__ h0d, const float* __restrict__ wn,
    const int* __restrict__ rp, const int* __restrict__ csr,
    const float* __restrict__ bias, float* __restrict__ act) {
    __shared__ float sw_[4][64];
    __shared__ int   ss_[4][64];
    int wid = threadIdx.x >> 6, lane = threadIdx.x & 63;
    int shard = blockIdx.x & 3;
    int node = (blockIdx.x >> 2) * 4 + wid;
    int q = lane >> 4, ql = lane & 15;
    int start = rp[node], end = rp[node + 1];
    const unsigned int* hp = h0d + shard * 16 + ql;
    float a0 = 0.f, a1 = 0.f;
    for (int base = start; base < end; base += 64) {
        int mm = end - base; if (mm > 64) mm = 64;
        int s_l = 0; float w_l = 0.f;
        if (lane < mm) {
            s_l = csr[base + lane];
            w_l = wn[base + lane];
        }
        ss_[wid][lane] = s_l;      // slots >= mm: s=0, w=0 -> contribute 0
        sw_[wid][lane] = w_l;      // wave-local LDS: no barrier needed
        for (int jj = 0; jj < mm; jj += 16) {
            int i0 = jj + q, i1 = i0 + 4, i2 = i0 + 8, i3 = i0 + 12;
            int   s0 = ss_[wid][i0], s1 = ss_[wid][i1], s2 = ss_[wid][i2], s3 = ss_[wid][i3];
            float w0 = sw_[wid][i0], w1 = sw_[wid][i1], w2 = sw_[wid][i2], w3 = sw_[wid][i3];
            unsigned u0 = hp[(size_t)s0 * 64];
            unsigned u1 = hp[(size_t)s1 * 64];
            unsigned u2 = hp[(size_t)s2 * 64];
            unsigned u3 = hp[(size_t)s3 * 64];
            a0 += w0 * blo(u0) + w1 * blo(u1) + w2 * blo(u2) + w3 * blo(u3);
            a1 += w0 * bhi(u0) + w1 * bhi(u1) + w2 * bhi(u2) + w3 * bhi(u3);
        }
    }
    a0 += __shfl_xor(a0, 16); a0 += __shfl_xor(a0, 32);
    a1 += __shfl_xor(a1, 16); a1 += __shfl_xor(a1, 32);
    if (lane < 16) {
        float2 b2 = *(const float2*)&bias[shard * 32 + ql * 2];
        float2 r;
        r.x = fmaxf(a0 + b2.x, 0.f);
        r.y = fmaxf(a1 + b2.y, 0.f);
        *(float2*)&act[(size_t)node * HID + shard * 32 + ql * 2] = r;
    }
}

// ---------------- Layer 1 GEMM: h1(bf16, x2 replicas) = act @ W1^T + dots ------
__global__ __launch_bounds__(128) void k_gemm1(
    const float* __restrict__ act, const float* __restrict__ W1,
    const float* __restrict__ a_s, const float* __restrict__ a_d,
    unsigned int* __restrict__ h1d, float* __restrict__ as1, float* __restrict__ ad1) {
    __shared__ float w1l[NCLS * HID];
    __shared__ float av[NCLS], adv[NCLS];
    int t = threadIdx.x;
    #pragma unroll
    for (int i = 0; i < 10; ++i) {
        int j = t + 128 * i;
        ((float4*)w1l)[j] = ((const float4*)W1)[j];
    }
    if (t < NCLS) { av[t] = a_s[t]; adv[t] = a_d[t]; }
    __syncthreads();
    int n = blockIdx.x * 128 + t;
    if (n >= N_NODES) return;
    const float4* ar = (const float4*)(act + (size_t)n * HID);
    float acc[NCLS];
    #pragma unroll
    for (int c = 0; c < NCLS; ++c) acc[c] = 0.f;
    for (int k0 = 0; k0 < HID; k0 += 4) {
        float4 xv = ar[k0 >> 2];
        #pragma unroll
        for (int c = 0; c < NCLS; ++c) {
            const float4 wv = *(const float4*)&w1l[c * HID + k0];
            acc[c] += xv.x * wv.x + xv.y * wv.y + xv.z * wv.z + xv.w * wv.w;
        }
    }
    float ps = 0.f, pd = 0.f;
    #pragma unroll
    for (int c = 0; c < NCLS; ++c) { ps += acc[c] * av[c]; pd += acc[c] * adv[c]; }
    unsigned pk_[20];
    #pragma unroll
    for (int c = 0; c < 20; ++c) pk_[c] = pk2(acc[2 * c], acc[2 * c + 1]);
    #pragma unroll
    for (int r = 0; r < 2; ++r)
        #pragma unroll
        for (int i = 0; i < 5; ++i)
            *(uint4*)&h1d[(size_t)r * R1D + (size_t)n * 20 + i * 4] =
                make_uint4(pk_[4*i], pk_[4*i+1], pk_[4*i+2], pk_[4*i+3]);
    as1[n] = ps; ad1[n] = pd;
}

// ---------------- Aggregation layer 1 (bf16 h1, 2 replicas) → fp32 output ------
__global__ __launch_bounds__(256) void k_agg1(
    const unsigned int* __restrict__ h1u, const float* __restrict__ wn,
    const int* __restrict__ rp, const int* __restrict__ csr,
    const float* __restrict__ bias, float* __restrict__ out) {
    __shared__ float sw_[4][64];
    __shared__ int   ss_[4][64];
    int wid = threadIdx.x >> 6, lane = threadIdx.x & 63;
    int half = lane >> 5, sl = lane & 31;
    int off20 = (sl < 20) ? sl : 0;    // lanes 20-31 read col 0 (discarded)
    int node = blockIdx.x * 4 + wid;
    int rep = blockIdx.x & 1;
    int start = rp[node], end = rp[node + 1];
    const unsigned int* hp = h1u + (size_t)rep * R1D + off20;
    float a0 = 0.f, a1 = 0.f;
    for (int base = start; base < end; base += 64) {
        int mm = end - base; if (mm > 64) mm = 64;
        int s_l = 0; float w_l = 0.f;
        if (lane < mm) {
            s_l = csr[base + lane];
            w_l = wn[base + lane];
        }
        ss_[wid][lane] = s_l;
        sw_[wid][lane] = w_l;
        for (int jj = 0; jj < mm; jj += 8) {
            int i0 = jj + half, i1 = i0 + 2, i2 = i0 + 4, i3 = i0 + 6;
            int   s0 = ss_[wid][i0], s1 = ss_[wid][i1], s2 = ss_[wid][i2], s3 = ss_[wid][i3];
            float w0 = sw_[wid][i0], w1 = sw_[wid][i1], w2 = sw_[wid][i2], w3 = sw_[wid][i3];
            unsigned u0 = hp[(size_t)s0 * 20];
            unsigned u1 = hp[(size_t)s1 * 20];
            unsigned u2 = hp[(size_t)s2 * 20];
            unsigned u3 = hp[(size_t)s3 * 20];
            a0 += w0 * blo(u0) + w1 * blo(u1) + w2 * blo(u2) + w3 * blo(u3);
            a1 += w0 * bhi(u0) + w1 * bhi(u1) + w2 * bhi(u2) + w3 * bhi(u3);
        }
    }
    a0 += __shfl_xor(a0, 32);
    a1 += __shfl_xor(a1, 32);
    if (half == 0 && sl < 20) {
        float2 r;
        r.x = a0 + bias[sl * 2];
        r.y = a1 + bias[sl * 2 + 1];
        *(float2*)&out[(size_t)node * NCLS + sl * 2] = r;
    }
}

extern "C" void kernel_launch(void* const* d_in, const int* in_sizes, int n_in,
                              void* d_out, int out_size, void* d_ws, size_t ws_size,
                              hipStream_t stream) {
    const float* x    = (const float*)d_in[0];
    const int*   ei   = (const int*)d_in[1];
    const float* W0   = (const float*)d_in[2];
    const float* a_s0 = (const float*)d_in[3];
    const float* a_d0 = (const float*)d_in[4];
    const float* b0   = (const float*)d_in[5];
    const float* W1   = (const float*)d_in[6];
    const float* a_s1 = (const float*)d_in[7];
    const float* a_d1 = (const float*)d_in[8];
    const float* b1   = (const float*)d_in[9];

    char* p = (char*)d_ws;
    auto alloc = [&](size_t bytes) { void* q = p; p += (bytes + 255) & ~size_t(255); return q; };
    unsigned short* h0b = (unsigned short*)alloc((size_t)N_NODES * HID * 2);   // bf16 (aliases buf)
    unsigned int*   buf = (unsigned int*)h0b;   // CSR staging: consumed before gemm0 writes h0b
    unsigned int*   h1d = (unsigned int*)alloc((size_t)2 * R1D * 4);           // bf16 x2 replicas
    float* act    = (float*)alloc((size_t)N_NODES * HID * 4);
    float* as0    = (float*)alloc((size_t)N_NODES * 4);
    float* ad0    = (float*)alloc((size_t)N_NODES * 4);
    float* as1    = (float*)alloc((size_t)N_NODES * 4);
    float* ad1    = (float*)alloc((size_t)N_NODES * 4);
    int*   rp     = (int*)alloc((size_t)(N_NODES + 1) * 4);
    int*   csr    = (int*)alloc((size_t)ET * 4);
    float* wn     = (float*)alloc((size_t)ET * 4);
    int*   bcnt   = (int*)alloc((size_t)NBUCK * 4);
    int*   cstart = (int*)alloc((size_t)(NBUCK + 1) * 4);
    int*   cursor = (int*)alloc((size_t)NBUCK * 4);

    const int binWGs = (ET + CHUNK - 1) / CHUNK;
    hipMemsetAsync(bcnt, 0, (size_t)NBUCK * 4, stream);
    k_bin_count<<<binWGs, 256, 0, stream>>>(ei, bcnt);
    k_bin_scan<<<1, 512, 0, stream>>>(bcnt, cstart, cursor, rp);
    k_bin_scatter<<<binWGs, 256, 0, stream>>>(ei, cursor, buf);
    k_bucket_build<<<NBUCK, 256, 0, stream>>>(buf, cstart, rp, csr);
    k_gemm0<<<(N_NODES + 63) / 64, 256, 0, stream>>>(x, W0, a_s0, a_d0, h0b, as0, ad0);
    k_wts<<<N_NODES / 4, 256, 0, stream>>>(as0, ad0, rp, csr, wn);
    k_agg0<<<N_NODES, 256, 0, stream>>>((const unsigned int*)h0b, wn, rp, csr, b0, act);
    k_gemm1<<<(N_NODES + 127) / 128, 128, 0, stream>>>(act, W1, a_s1, a_d1, h1d, as1, ad1);
    k_wts<<<N_NODES / 4, 256, 0, stream>>>(as1, ad1, rp, csr, wn);
    k_agg1<<<N_NODES / 4, 256, 0, stream>>>(h1d, wn, rp, csr, b1, (float*)d_out);
}

// Round 10
// 297.304 us; speedup vs baseline: 1.2013x; 1.2013x over previous
//
#include <hip/hip_runtime.h>
#include <hip/hip_bf16.h>

#define N_NODES 50000
#define N_EDGES 1600000
#define ET (N_EDGES + N_NODES)   // self-loops appended
#define IN_DIM 256
#define HID 128
#define NCLS 40
#define NEG 0.2f
#define NBUCK 391                // ceil(50000 / 128) buckets of 128 dst nodes
#define CHUNK 4096               // edges per binning workgroup

typedef short bf16x8 __attribute__((ext_vector_type(8)));
typedef float f32x4  __attribute__((ext_vector_type(4)));

__device__ __forceinline__ unsigned pk2(float a, float b) {
    __hip_bfloat16 ha = __float2bfloat16(a), hb = __float2bfloat16(b);
    unsigned short ua = *(unsigned short*)&ha, ub = *(unsigned short*)&hb;
    return (unsigned)ua | ((unsigned)ub << 16);
}
__device__ __forceinline__ float blo(unsigned u) { return __uint_as_float(u << 16); }
__device__ __forceinline__ float bhi(unsigned u) { return __uint_as_float(u & 0xffff0000u); }

// ---------------- CSR build: two-level binning (no per-edge global atomics) ----
__global__ __launch_bounds__(256) void k_bin_count(const int* __restrict__ ei,
                                                   int* __restrict__ bcnt) {
    __shared__ int hist[NBUCK];
    int t = threadIdx.x;
    for (int i = t; i < NBUCK; i += 256) hist[i] = 0;
    __syncthreads();
    int base = blockIdx.x * CHUNK;
    #pragma unroll
    for (int j = 0; j < 16; ++j) {
        int i = base + j * 256 + t;
        if (i < ET) {
            int d = (i < N_EDGES) ? ei[N_EDGES + i] : (i - N_EDGES);
            atomicAdd(&hist[d >> 7], 1);
        }
    }
    __syncthreads();
    for (int i = t; i < NBUCK; i += 256) if (hist[i]) atomicAdd(&bcnt[i], hist[i]);
}

__global__ __launch_bounds__(512) void k_bin_scan(const int* __restrict__ bcnt,
                                                  int* __restrict__ cstart,
                                                  int* __restrict__ cursor,
                                                  int* __restrict__ rp) {
    __shared__ int s[512];
    int t = threadIdx.x;
    int v = (t < NBUCK) ? bcnt[t] : 0;
    s[t] = v;
    __syncthreads();
    for (int off = 1; off < 512; off <<= 1) {
        int u = (t >= off) ? s[t - off] : 0;
        __syncthreads();
        s[t] += u;
        __syncthreads();
    }
    int ex = s[t] - v;   // exclusive prefix
    if (t < NBUCK) { cstart[t] = ex; cursor[t] = ex; }
    if (t == 0) { cstart[NBUCK] = ET; rp[N_NODES] = ET; }
}

__global__ __launch_bounds__(256) void k_bin_scatter(const int* __restrict__ ei,
                                                     int* __restrict__ cursor,
                                                     unsigned int* __restrict__ buf) {
    __shared__ int sd[CHUNK];     // staged dst (or -1 past end)
    __shared__ int hist[NBUCK];
    __shared__ int wbase[NBUCK];
    int t = threadIdx.x;
    for (int i = t; i < NBUCK; i += 256) hist[i] = 0;
    __syncthreads();
    int base = blockIdx.x * CHUNK;
    #pragma unroll
    for (int j = 0; j < 16; ++j) {
        int i = base + j * 256 + t;
        int d = -1;
        if (i < ET) d = (i < N_EDGES) ? ei[N_EDGES + i] : (i - N_EDGES);
        sd[j * 256 + t] = d;
        if (d >= 0) atomicAdd(&hist[d >> 7], 1);
    }
    __syncthreads();
    for (int i = t; i < NBUCK; i += 256) {
        int h = hist[i];
        wbase[i] = h ? atomicAdd(&cursor[i], h) : 0;
        hist[i] = 0;              // reuse as running offset
    }
    __syncthreads();
    #pragma unroll
    for (int j = 0; j < 16; ++j) {
        int i = base + j * 256 + t;
        int d = sd[j * 256 + t];
        if (d >= 0) {
            int s_ = (i < N_EDGES) ? ei[i] : d;
            int b = d >> 7;
            int off = atomicAdd(&hist[b], 1);
            buf[wbase[b] + off] = ((unsigned)(d & 127) << 16) | (unsigned)s_;
        }
    }
}

__global__ __launch_bounds__(256) void k_bucket_build(const unsigned int* __restrict__ buf,
                                                      const int* __restrict__ cstart,
                                                      int* __restrict__ rp,
                                                      int* __restrict__ csr) {
    __shared__ int cnt[128], rpl[128], cur[128];
    int b = blockIdx.x;
    int t = threadIdx.x;
    int lo = cstart[b], hi = cstart[b + 1];
    if (t < 128) cnt[t] = 0;
    __syncthreads();
    for (int i = lo + t; i < hi; i += 256) atomicAdd(&cnt[buf[i] >> 16], 1);
    __syncthreads();
    if (t == 0) {
        int run = 0;
        #pragma unroll
        for (int l = 0; l < 128; ++l) { rpl[l] = run; run += cnt[l]; }
    }
    __syncthreads();
    if (t < 128) {
        int node = b * 128 + t;
        if (node < N_NODES) rp[node] = lo + rpl[t];
        cur[t] = 0;
    }
    __syncthreads();
    for (int i = lo + t; i < hi; i += 256) {
        unsigned v = buf[i];
        int dl = v >> 16;
        int off = atomicAdd(&cur[dl], 1);
        csr[lo + rpl[dl] + off] = (int)(v & 0xffffu);
    }
}

// ---------------- Layer 0 GEMM (MFMA bf16): h0(bf16) = x @ W0^T + alpha dots ---
__global__ __launch_bounds__(256) void k_gemm0(
    const float* __restrict__ x, const float* __restrict__ W0,
    const float* __restrict__ a_s, const float* __restrict__ a_d,
    unsigned short* __restrict__ h0b, float* __restrict__ as0, float* __restrict__ ad0) {
    __shared__ unsigned sA[64 * 36];    // bf16 [64 rows][72]
    __shared__ unsigned sB[128 * 36];   // bf16 [128 cols][72]
    int t = threadIdx.x;
    int n0 = blockIdx.x * 64;
    int w = t >> 6, lane = t & 63;
    int rw = lane & 15, q = lane >> 4;
    f32x4 acc[8];
    #pragma unroll
    for (int n = 0; n < 8; ++n) acc[n] = (f32x4){0.f, 0.f, 0.f, 0.f};

    for (int kc = 0; kc < IN_DIM; kc += 64) {
        #pragma unroll
        for (int i = 0; i < 4; ++i) {
            int f = i * 256 + t;
            int r = f >> 4, fq = f & 15;
            float4 v = make_float4(0.f, 0.f, 0.f, 0.f);
            if (n0 + r < N_NODES)
                v = *(const float4*)&x[(size_t)(n0 + r) * IN_DIM + kc + fq * 4];
            *(uint2*)&sA[r * 36 + fq * 2] = make_uint2(pk2(v.x, v.y), pk2(v.z, v.w));
        }
        #pragma unroll
        for (int i = 0; i < 8; ++i) {
            int f = i * 256 + t;
            int c = f >> 4, fq = f & 15;
            float4 v = *(const float4*)&W0[(size_t)c * IN_DIM + kc + fq * 4];
            *(uint2*)&sB[c * 36 + fq * 2] = make_uint2(pk2(v.x, v.y), pk2(v.z, v.w));
        }
        __syncthreads();
        #pragma unroll
        for (int ks = 0; ks < 2; ++ks) {
            bf16x8 af = *(const bf16x8*)((const unsigned short*)sA + (16 * w + rw) * 72 + ks * 32 + q * 8);
            #pragma unroll
            for (int n = 0; n < 8; ++n) {
                bf16x8 bfr = *(const bf16x8*)((const unsigned short*)sB + (n * 16 + rw) * 72 + ks * 32 + q * 8);
                acc[n] = __builtin_amdgcn_mfma_f32_16x16x32_bf16(af, bfr, acc[n], 0, 0, 0);
            }
        }
        __syncthreads();
    }

    float asv[8], adv[8];
    #pragma unroll
    for (int n = 0; n < 8; ++n) { asv[n] = a_s[n * 16 + rw]; adv[n] = a_d[n * 16 + rw]; }
    float ps[4] = {0.f, 0.f, 0.f, 0.f}, pd[4] = {0.f, 0.f, 0.f, 0.f};
    #pragma unroll
    for (int n = 0; n < 8; ++n)
        #pragma unroll
        for (int reg = 0; reg < 4; ++reg) {
            float vv = acc[n][reg];
            ps[reg] += vv * asv[n];
            pd[reg] += vv * adv[n];
        }
    #pragma unroll
    for (int reg = 0; reg < 4; ++reg) {
        int node = n0 + 16 * w + q * 4 + reg;
        if (node < N_NODES) {
            #pragma unroll
            for (int n = 0; n < 8; ++n) {
                __hip_bfloat16 hb = __float2bfloat16(acc[n][reg]);
                h0b[(size_t)node * HID + n * 16 + rw] = *(unsigned short*)&hb;
            }
        }
    }
    #pragma unroll
    for (int reg = 0; reg < 4; ++reg)
        #pragma unroll
        for (int off = 1; off < 16; off <<= 1) {
            ps[reg] += __shfl_xor(ps[reg], off);
            pd[reg] += __shfl_xor(pd[reg], off);
        }
    if (rw == 0) {
        #pragma unroll
        for (int reg = 0; reg < 4; ++reg) {
            int node = n0 + 16 * w + q * 4 + reg;
            if (node < N_NODES) { as0[node] = ps[reg]; ad0[node] = pd[reg]; }
        }
    }
}

// ---------------- Aggregation layer 0 (bf16 h0): wave/node, quarter-wave rows --
// 16 lanes x uint4 = one full 256B row per load instr; 4 rows/instr, 16 in flight.
__global__ __launch_bounds__(256) void k_agg0(
    const uint4* __restrict__ h0q, const float* __restrict__ as, const float* __restrict__ ad,
    const int* __restrict__ rp, const int* __restrict__ csr,
    const float* __restrict__ bias, float* __restrict__ act) {
    __shared__ float sw_[4][64];
    __shared__ int   ss_[4][64];
    int wid = threadIdx.x >> 6, lane = threadIdx.x & 63;
    int q = lane >> 4, ql = lane & 15;
    int node = blockIdx.x * 4 + wid;
    int start = rp[node], end = rp[node + 1];
    float ad_n = ad[node];
    float a0 = 0.f, a1 = 0.f, a2 = 0.f, a3 = 0.f;
    float a4 = 0.f, a5 = 0.f, a6 = 0.f, a7 = 0.f, den = 0.f;
    for (int base = start; base < end; base += 64) {
        int mm = end - base; if (mm > 64) mm = 64;
        int s_l = 0; float w_l = 0.f;
        if (lane < mm) {
            s_l = csr[base + lane];
            float e = as[s_l] + ad_n;
            e = (e > 0.f) ? e : NEG * e;
            w_l = __expf(e);
            den += w_l;
        }
        ss_[wid][lane] = s_l;      // all 64 slots written; slots >= mm: s=0, w=0
        sw_[wid][lane] = w_l;      // wave-local LDS: no barrier needed
        for (int jj = 0; jj < mm; jj += 16) {
            int i0 = jj + q, i1 = i0 + 4, i2 = i0 + 8, i3 = i0 + 12;
            int   s0 = ss_[wid][i0], s1 = ss_[wid][i1], s2 = ss_[wid][i2], s3 = ss_[wid][i3];
            float w0 = sw_[wid][i0], w1 = sw_[wid][i1], w2 = sw_[wid][i2], w3 = sw_[wid][i3];
            uint4 u0 = h0q[(size_t)s0 * 16 + ql];
            uint4 u1 = h0q[(size_t)s1 * 16 + ql];
            uint4 u2 = h0q[(size_t)s2 * 16 + ql];
            uint4 u3 = h0q[(size_t)s3 * 16 + ql];
            a0 += w0 * blo(u0.x) + w1 * blo(u1.x) + w2 * blo(u2.x) + w3 * blo(u3.x);
            a1 += w0 * bhi(u0.x) + w1 * bhi(u1.x) + w2 * bhi(u2.x) + w3 * bhi(u3.x);
            a2 += w0 * blo(u0.y) + w1 * blo(u1.y) + w2 * blo(u2.y) + w3 * blo(u3.y);
            a3 += w0 * bhi(u0.y) + w1 * bhi(u1.y) + w2 * bhi(u2.y) + w3 * bhi(u3.y);
            a4 += w0 * blo(u0.z) + w1 * blo(u1.z) + w2 * blo(u2.z) + w3 * blo(u3.z);
            a5 += w0 * bhi(u0.z) + w1 * bhi(u1.z) + w2 * bhi(u2.z) + w3 * bhi(u3.z);
            a6 += w0 * blo(u0.w) + w1 * blo(u1.w) + w2 * blo(u2.w) + w3 * blo(u3.w);
            a7 += w0 * bhi(u0.w) + w1 * bhi(u1.w) + w2 * bhi(u2.w) + w3 * bhi(u3.w);
        }
    }
    #pragma unroll
    for (int off = 32; off; off >>= 1) den += __shfl_xor(den, off);
    a0 += __shfl_xor(a0, 16); a0 += __shfl_xor(a0, 32);
    a1 += __shfl_xor(a1, 16); a1 += __shfl_xor(a1, 32);
    a2 += __shfl_xor(a2, 16); a2 += __shfl_xor(a2, 32);
    a3 += __shfl_xor(a3, 16); a3 += __shfl_xor(a3, 32);
    a4 += __shfl_xor(a4, 16); a4 += __shfl_xor(a4, 32);
    a5 += __shfl_xor(a5, 16); a5 += __shfl_xor(a5, 32);
    a6 += __shfl_xor(a6, 16); a6 += __shfl_xor(a6, 32);
    a7 += __shfl_xor(a7, 16); a7 += __shfl_xor(a7, 32);
    if (lane < 16) {
        float inv = 1.f / fmaxf(den, 1e-16f);
        float4 b0v = *(const float4*)&bias[ql * 8];
        float4 b1v = *(const float4*)&bias[ql * 8 + 4];
        float4 r0, r1;
        r0.x = fmaxf(a0 * inv + b0v.x, 0.f);
        r0.y = fmaxf(a1 * inv + b0v.y, 0.f);
        r0.z = fmaxf(a2 * inv + b0v.z, 0.f);
        r0.w = fmaxf(a3 * inv + b0v.w, 0.f);
        r1.x = fmaxf(a4 * inv + b1v.x, 0.f);
        r1.y = fmaxf(a5 * inv + b1v.y, 0.f);
        r1.z = fmaxf(a6 * inv + b1v.z, 0.f);
        r1.w = fmaxf(a7 * inv + b1v.w, 0.f);
        *(float4*)&act[(size_t)node * HID + ql * 8]     = r0;
        *(float4*)&act[(size_t)node * HID + ql * 8 + 4] = r1;
    }
}

// ---------------- Layer 1 GEMM: h1(bf16) = act @ W1^T, fused alpha dots --------
__global__ __launch_bounds__(128) void k_gemm1(
    const float* __restrict__ act, const float* __restrict__ W1,
    const float* __restrict__ a_s, const float* __restrict__ a_d,
    unsigned short* __restrict__ h1b, float* __restrict__ as1, float* __restrict__ ad1) {
    __shared__ float w1l[NCLS * HID];
    __shared__ float av[NCLS], adv[NCLS];
    int t = threadIdx.x;
    #pragma unroll
    for (int i = 0; i < 10; ++i) {
        int j = t + 128 * i;
        ((float4*)w1l)[j] = ((const float4*)W1)[j];
    }
    if (t < NCLS) { av[t] = a_s[t]; adv[t] = a_d[t]; }
    __syncthreads();
    int n = blockIdx.x * 128 + t;
    if (n >= N_NODES) return;
    const float4* ar = (const float4*)(act + (size_t)n * HID);
    float acc[NCLS];
    #pragma unroll
    for (int c = 0; c < NCLS; ++c) acc[c] = 0.f;
    for (int k0 = 0; k0 < HID; k0 += 4) {
        float4 xv = ar[k0 >> 2];
        #pragma unroll
        for (int c = 0; c < NCLS; ++c) {
            const float4 wv = *(const float4*)&w1l[c * HID + k0];
            acc[c] += xv.x * wv.x + xv.y * wv.y + xv.z * wv.z + xv.w * wv.w;
        }
    }
    float ps = 0.f, pd = 0.f;
    #pragma unroll
    for (int c = 0; c < NCLS; ++c) { ps += acc[c] * av[c]; pd += acc[c] * adv[c]; }
    unsigned pk_[20];
    #pragma unroll
    for (int c = 0; c < 20; ++c) pk_[c] = pk2(acc[2 * c], acc[2 * c + 1]);
    #pragma unroll
    for (int i = 0; i < 5; ++i)
        *(uint4*)&h1b[(size_t)n * NCLS + i * 8] = make_uint4(pk_[4*i], pk_[4*i+1], pk_[4*i+2], pk_[4*i+3]);
    as1[n] = ps; ad1[n] = pd;
}

// ---------------- Aggregation layer 1 (bf16 h1, C=40): quarter-wave uint2 ------
__global__ __launch_bounds__(256) void k_agg1(
    const uint2* __restrict__ h1u, const float* __restrict__ as, const float* __restrict__ ad,
    const int* __restrict__ rp, const int* __restrict__ csr,
    const float* __restrict__ bias, float* __restrict__ out) {
    __shared__ float sw_[4][64];
    __shared__ int   ss_[4][64];
    int wid = threadIdx.x >> 6, lane = threadIdx.x & 63;
    int q = lane >> 4, ql = lane & 15;
    int off10 = (ql < 10) ? ql : 0;   // lanes 10-15 of each group read col 0 (discarded)
    int node = blockIdx.x * 4 + wid;
    int start = rp[node], end = rp[node + 1];
    float ad_n = ad[node];
    float a0 = 0.f, a1 = 0.f, a2 = 0.f, a3 = 0.f, den = 0.f;
    for (int base = start; base < end; base += 64) {
        int mm = end - base; if (mm > 64) mm = 64;
        int s_l = 0; float w_l = 0.f;
        if (lane < mm) {
            s_l = csr[base + lane];
            float e = as[s_l] + ad_n;
            e = (e > 0.f) ? e : NEG * e;
            w_l = __expf(e);
            den += w_l;
        }
        ss_[wid][lane] = s_l;
        sw_[wid][lane] = w_l;
        for (int jj = 0; jj < mm; jj += 16) {
            int i0 = jj + q, i1 = i0 + 4, i2 = i0 + 8, i3 = i0 + 12;
            int   s0 = ss_[wid][i0], s1 = ss_[wid][i1], s2 = ss_[wid][i2], s3 = ss_[wid][i3];
            float w0 = sw_[wid][i0], w1 = sw_[wid][i1], w2 = sw_[wid][i2], w3 = sw_[wid][i3];
            uint2 u0 = h1u[(size_t)s0 * 10 + off10];
            uint2 u1 = h1u[(size_t)s1 * 10 + off10];
            uint2 u2 = h1u[(size_t)s2 * 10 + off10];
            uint2 u3 = h1u[(size_t)s3 * 10 + off10];
            a0 += w0 * blo(u0.x) + w1 * blo(u1.x) + w2 * blo(u2.x) + w3 * blo(u3.x);
            a1 += w0 * bhi(u0.x) + w1 * bhi(u1.x) + w2 * bhi(u2.x) + w3 * bhi(u3.x);
            a2 += w0 * blo(u0.y) + w1 * blo(u1.y) + w2 * blo(u2.y) + w3 * blo(u3.y);
            a3 += w0 * bhi(u0.y) + w1 * bhi(u1.y) + w2 * bhi(u2.y) + w3 * bhi(u3.y);
        }
    }
    #pragma unroll
    for (int off = 32; off; off >>= 1) den += __shfl_xor(den, off);
    a0 += __shfl_xor(a0, 16); a0 += __shfl_xor(a0, 32);
    a1 += __shfl_xor(a1, 16); a1 += __shfl_xor(a1, 32);
    a2 += __shfl_xor(a2, 16); a2 += __shfl_xor(a2, 32);
    a3 += __shfl_xor(a3, 16); a3 += __shfl_xor(a3, 32);
    if (lane < 10) {
        float inv = 1.f / fmaxf(den, 1e-16f);
        float4 b4 = *(const float4*)&bias[ql * 4];
        float4 r;
        r.x = a0 * inv + b4.x;
        r.y = a1 * inv + b4.y;
        r.z = a2 * inv + b4.z;
        r.w = a3 * inv + b4.w;
        *(float4*)&out[(size_t)node * NCLS + ql * 4] = r;
    }
}

extern "C" void kernel_launch(void* const* d_in, const int* in_sizes, int n_in,
                              void* d_out, int out_size, void* d_ws, size_t ws_size,
                              hipStream_t stream) {
    const float* x    = (const float*)d_in[0];
    const int*   ei   = (const int*)d_in[1];
    const float* W0   = (const float*)d_in[2];
    const float* a_s0 = (const float*)d_in[3];
    const float* a_d0 = (const float*)d_in[4];
    const float* b0   = (const float*)d_in[5];
    const float* W1   = (const float*)d_in[6];
    const float* a_s1 = (const float*)d_in[7];
    const float* a_d1 = (const float*)d_in[8];
    const float* b1   = (const float*)d_in[9];

    char* p = (char*)d_ws;
    auto alloc = [&](size_t bytes) { void* q = p; p += (bytes + 255) & ~size_t(255); return q; };
    unsigned short* h0b = (unsigned short*)alloc((size_t)N_NODES * HID * 2);   // bf16 (aliases buf)
    unsigned int*   buf = (unsigned int*)h0b;   // CSR staging: consumed before gemm0 writes h0b
    unsigned short* h1b = (unsigned short*)alloc(((size_t)N_NODES * NCLS + 32) * 2); // bf16 (+pad)
    float* act    = (float*)alloc((size_t)N_NODES * HID * 4);
    float* as0    = (float*)alloc((size_t)N_NODES * 4);
    float* ad0    = (float*)alloc((size_t)N_NODES * 4);
    float* as1    = (float*)alloc((size_t)N_NODES * 4);
    float* ad1    = (float*)alloc((size_t)N_NODES * 4);
    int*   rp     = (int*)alloc((size_t)(N_NODES + 1) * 4);
    int*   csr    = (int*)alloc((size_t)ET * 4);
    int*   bcnt   = (int*)alloc((size_t)NBUCK * 4);
    int*   cstart = (int*)alloc((size_t)(NBUCK + 1) * 4);
    int*   cursor = (int*)alloc((size_t)NBUCK * 4);

    const int binWGs = (ET + CHUNK - 1) / CHUNK;
    hipMemsetAsync(bcnt, 0, (size_t)NBUCK * 4, stream);
    k_bin_count<<<binWGs, 256, 0, stream>>>(ei, bcnt);
    k_bin_scan<<<1, 512, 0, stream>>>(bcnt, cstart, cursor, rp);
    k_bin_scatter<<<binWGs, 256, 0, stream>>>(ei, cursor, buf);
    k_bucket_build<<<NBUCK, 256, 0, stream>>>(buf, cstart, rp, csr);
    k_gemm0<<<(N_NODES + 63) / 64, 256, 0, stream>>>(x, W0, a_s0, a_d0, h0b, as0, ad0);
    k_agg0<<<N_NODES / 4, 256, 0, stream>>>((const uint4*)h0b, as0, ad0, rp, csr, b0, act);
    k_gemm1<<<(N_NODES + 127) / 128, 128, 0, stream>>>(act, W1, a_s1, a_d1, h1b, as1, ad1);
    k_agg1<<<N_NODES / 4, 256, 0, stream>>>((const uint2*)h1b, as1, ad1, rp, csr, b1, (float*)d_out);
}

// Round 11
// 284.418 us; speedup vs baseline: 1.2557x; 1.0453x over previous
//
#include <hip/hip_runtime.h>
#include <hip/hip_bf16.h>

#define N_NODES 50000
#define N_EDGES 1600000
#define ET (N_EDGES + N_NODES)   // self-loops appended
#define IN_DIM 256
#define HID 128
#define NCLS 40
#define NEG 0.2f
#define NBUCK 391                // ceil(50000 / 128) buckets of 128 dst nodes
#define CHUNK 8192               // edges per binning workgroup
#define CAP 5120                 // fixed bucket capacity (mean 4224, sigma ~65)

typedef short bf16x8 __attribute__((ext_vector_type(8)));
typedef float f32x4  __attribute__((ext_vector_type(4)));

__device__ __forceinline__ unsigned pk2(float a, float b) {
    __hip_bfloat16 ha = __float2bfloat16(a), hb = __float2bfloat16(b);
    unsigned short ua = *(unsigned short*)&ha, ub = *(unsigned short*)&hb;
    return (unsigned)ua | ((unsigned)ub << 16);
}
__device__ __forceinline__ float blo(unsigned u) { return __uint_as_float(u << 16); }
__device__ __forceinline__ float bhi(unsigned u) { return __uint_as_float(u & 0xffff0000u); }

// ---------------- CSR build: fixed-capacity binning (no count pass) ------------
__global__ void k_init(int* __restrict__ cursor) {
    int i = blockIdx.x * 256 + threadIdx.x;
    if (i < NBUCK) cursor[i] = i * CAP;
}

__global__ __launch_bounds__(256) void k_bin_scatter(const int* __restrict__ ei,
                                                     int* __restrict__ cursor,
                                                     unsigned int* __restrict__ buf) {
    __shared__ int sd[CHUNK];     // staged dst (or -1 past end)
    __shared__ int hist[NBUCK];
    __shared__ int wbase[NBUCK];
    int t = threadIdx.x;
    for (int i = t; i < NBUCK; i += 256) hist[i] = 0;
    __syncthreads();
    int base = blockIdx.x * CHUNK;
    #pragma unroll
    for (int j = 0; j < 32; ++j) {
        int i = base + j * 256 + t;
        int d = -1;
        if (i < ET) d = (i < N_EDGES) ? ei[N_EDGES + i] : (i - N_EDGES);
        sd[j * 256 + t] = d;
        if (d >= 0) atomicAdd(&hist[d >> 7], 1);
    }
    __syncthreads();
    for (int i = t; i < NBUCK; i += 256) {
        int h = hist[i];
        wbase[i] = h ? atomicAdd(&cursor[i], h) : 0;
        hist[i] = 0;              // reuse as running offset
    }
    __syncthreads();
    #pragma unroll
    for (int j = 0; j < 32; ++j) {
        int i = base + j * 256 + t;
        int d = sd[j * 256 + t];
        if (d >= 0) {
            int s_ = (i < N_EDGES) ? ei[i] : d;
            int b = d >> 7;
            int off = atomicAdd(&hist[b], 1);
            buf[wbase[b] + off] = ((unsigned)(d & 127) << 16) | (unsigned)s_;
        }
    }
}

// scan over per-bucket counts (cursor[b]-b*CAP) -> global csr offsets
__global__ __launch_bounds__(512) void k_bin_scan(const int* __restrict__ cursor,
                                                  int* __restrict__ cstart,
                                                  int* __restrict__ rp) {
    __shared__ int s[512];
    int t = threadIdx.x;
    int v = (t < NBUCK) ? (cursor[t] - t * CAP) : 0;
    s[t] = v;
    __syncthreads();
    for (int off = 1; off < 512; off <<= 1) {
        int u = (t >= off) ? s[t - off] : 0;
        __syncthreads();
        s[t] += u;
        __syncthreads();
    }
    int ex = s[t] - v;   // exclusive prefix
    if (t < NBUCK) cstart[t] = ex;
    if (t == 0) rp[N_NODES] = ET;
}

__global__ __launch_bounds__(256) void k_bucket_build(const unsigned int* __restrict__ buf,
                                                      const int* __restrict__ cursor,
                                                      const int* __restrict__ cstart,
                                                      int* __restrict__ rp,
                                                      int* __restrict__ csr) {
    __shared__ int cnt[128], rpl[128], cur[128];
    int b = blockIdx.x;
    int t = threadIdx.x;
    int lo = b * CAP, hi = cursor[b];
    int g = cstart[b];
    if (t < 128) cnt[t] = 0;
    __syncthreads();
    for (int i = lo + t; i < hi; i += 256) atomicAdd(&cnt[buf[i] >> 16], 1);
    __syncthreads();
    if (t == 0) {
        int run = 0;
        #pragma unroll
        for (int l = 0; l < 128; ++l) { rpl[l] = run; run += cnt[l]; }
    }
    __syncthreads();
    if (t < 128) {
        int node = b * 128 + t;
        if (node < N_NODES) rp[node] = g + rpl[t];
        cur[t] = 0;
    }
    __syncthreads();
    for (int i = lo + t; i < hi; i += 256) {
        unsigned v = buf[i];
        int dl = v >> 16;
        int off = atomicAdd(&cur[dl], 1);
        csr[g + rpl[dl] + off] = (int)(v & 0xffffu);
    }
}

// ---------------- Layer 0 GEMM (MFMA bf16): h0(bf16) = x @ W0^T + alpha dots ---
__global__ __launch_bounds__(256) void k_gemm0(
    const float* __restrict__ x, const float* __restrict__ W0,
    const float* __restrict__ a_s, const float* __restrict__ a_d,
    unsigned short* __restrict__ h0b, float* __restrict__ as0, float* __restrict__ ad0) {
    __shared__ unsigned sA[64 * 36];    // bf16 [64 rows][72]
    __shared__ unsigned sB[128 * 36];   // bf16 [128 cols][72]
    int t = threadIdx.x;
    int n0 = blockIdx.x * 64;
    int w = t >> 6, lane = t & 63;
    int rw = lane & 15, q = lane >> 4;
    f32x4 acc[8];
    #pragma unroll
    for (int n = 0; n < 8; ++n) acc[n] = (f32x4){0.f, 0.f, 0.f, 0.f};

    for (int kc = 0; kc < IN_DIM; kc += 64) {
        #pragma unroll
        for (int i = 0; i < 4; ++i) {
            int f = i * 256 + t;
            int r = f >> 4, fq = f & 15;
            float4 v = make_float4(0.f, 0.f, 0.f, 0.f);
            if (n0 + r < N_NODES)
                v = *(const float4*)&x[(size_t)(n0 + r) * IN_DIM + kc + fq * 4];
            *(uint2*)&sA[r * 36 + fq * 2] = make_uint2(pk2(v.x, v.y), pk2(v.z, v.w));
        }
        #pragma unroll
        for (int i = 0; i < 8; ++i) {
            int f = i * 256 + t;
            int c = f >> 4, fq = f & 15;
            float4 v = *(const float4*)&W0[(size_t)c * IN_DIM + kc + fq * 4];
            *(uint2*)&sB[c * 36 + fq * 2] = make_uint2(pk2(v.x, v.y), pk2(v.z, v.w));
        }
        __syncthreads();
        #pragma unroll
        for (int ks = 0; ks < 2; ++ks) {
            bf16x8 af = *(const bf16x8*)((const unsigned short*)sA + (16 * w + rw) * 72 + ks * 32 + q * 8);
            #pragma unroll
            for (int n = 0; n < 8; ++n) {
                bf16x8 bfr = *(const bf16x8*)((const unsigned short*)sB + (n * 16 + rw) * 72 + ks * 32 + q * 8);
                acc[n] = __builtin_amdgcn_mfma_f32_16x16x32_bf16(af, bfr, acc[n], 0, 0, 0);
            }
        }
        __syncthreads();
    }

    float asv[8], adv[8];
    #pragma unroll
    for (int n = 0; n < 8; ++n) { asv[n] = a_s[n * 16 + rw]; adv[n] = a_d[n * 16 + rw]; }
    float ps[4] = {0.f, 0.f, 0.f, 0.f}, pd[4] = {0.f, 0.f, 0.f, 0.f};
    #pragma unroll
    for (int n = 0; n < 8; ++n)
        #pragma unroll
        for (int reg = 0; reg < 4; ++reg) {
            float vv = acc[n][reg];
            ps[reg] += vv * asv[n];
            pd[reg] += vv * adv[n];
        }
    #pragma unroll
    for (int reg = 0; reg < 4; ++reg) {
        int node = n0 + 16 * w + q * 4 + reg;
        if (node < N_NODES) {
            #pragma unroll
            for (int n = 0; n < 8; ++n) {
                __hip_bfloat16 hb = __float2bfloat16(acc[n][reg]);
                h0b[(size_t)node * HID + n * 16 + rw] = *(unsigned short*)&hb;
            }
        }
    }
    #pragma unroll
    for (int reg = 0; reg < 4; ++reg)
        #pragma unroll
        for (int off = 1; off < 16; off <<= 1) {
            ps[reg] += __shfl_xor(ps[reg], off);
            pd[reg] += __shfl_xor(pd[reg], off);
        }
    if (rw == 0) {
        #pragma unroll
        for (int reg = 0; reg < 4; ++reg) {
            int node = n0 + 16 * w + q * 4 + reg;
            if (node < N_NODES) { as0[node] = ps[reg]; ad0[node] = pd[reg]; }
        }
    }
}

// ---------------- Aggregation layer 0 (bf16 h0): wave/node, quarter-wave rows --
// 16 lanes x uint4 = one full 256B row per load instr; act written bf16.
__global__ __launch_bounds__(256) void k_agg0(
    const uint4* __restrict__ h0q, const float* __restrict__ as, const float* __restrict__ ad,
    const int* __restrict__ rp, const int* __restrict__ csr,
    const float* __restrict__ bias, unsigned short* __restrict__ actb) {
    __shared__ float sw_[4][64];
    __shared__ int   ss_[4][64];
    int wid = threadIdx.x >> 6, lane = threadIdx.x & 63;
    int q = lane >> 4, ql = lane & 15;
    int node = blockIdx.x * 4 + wid;
    int start = rp[node], end = rp[node + 1];
    float ad_n = ad[node];
    float a0 = 0.f, a1 = 0.f, a2 = 0.f, a3 = 0.f;
    float a4 = 0.f, a5 = 0.f, a6 = 0.f, a7 = 0.f, den = 0.f;
    for (int base = start; base < end; base += 64) {
        int mm = end - base; if (mm > 64) mm = 64;
        int s_l = 0; float w_l = 0.f;
        if (lane < mm) {
            s_l = csr[base + lane];
            float e = as[s_l] + ad_n;
            e = (e > 0.f) ? e : NEG * e;
            w_l = __expf(e);
            den += w_l;
        }
        ss_[wid][lane] = s_l;      // slots >= mm: s=0, w=0 -> contribute 0
        sw_[wid][lane] = w_l;      // wave-local LDS: no barrier needed
        for (int jj = 0; jj < mm; jj += 16) {
            int i0 = jj + q, i1 = i0 + 4, i2 = i0 + 8, i3 = i0 + 12;
            int   s0 = ss_[wid][i0], s1 = ss_[wid][i1], s2 = ss_[wid][i2], s3 = ss_[wid][i3];
            float w0 = sw_[wid][i0], w1 = sw_[wid][i1], w2 = sw_[wid][i2], w3 = sw_[wid][i3];
            uint4 u0 = h0q[(size_t)s0 * 16 + ql];
            uint4 u1 = h0q[(size_t)s1 * 16 + ql];
            uint4 u2 = h0q[(size_t)s2 * 16 + ql];
            uint4 u3 = h0q[(size_t)s3 * 16 + ql];
            a0 += w0 * blo(u0.x) + w1 * blo(u1.x) + w2 * blo(u2.x) + w3 * blo(u3.x);
            a1 += w0 * bhi(u0.x) + w1 * bhi(u1.x) + w2 * bhi(u2.x) + w3 * bhi(u3.x);
            a2 += w0 * blo(u0.y) + w1 * blo(u1.y) + w2 * blo(u2.y) + w3 * blo(u3.y);
            a3 += w0 * bhi(u0.y) + w1 * bhi(u1.y) + w2 * bhi(u2.y) + w3 * bhi(u3.y);
            a4 += w0 * blo(u0.z) + w1 * blo(u1.z) + w2 * blo(u2.z) + w3 * blo(u3.z);
            a5 += w0 * bhi(u0.z) + w1 * bhi(u1.z) + w2 * bhi(u2.z) + w3 * bhi(u3.z);
            a6 += w0 * blo(u0.w) + w1 * blo(u1.w) + w2 * blo(u2.w) + w3 * blo(u3.w);
            a7 += w0 * bhi(u0.w) + w1 * bhi(u1.w) + w2 * bhi(u2.w) + w3 * bhi(u3.w);
        }
    }
    #pragma unroll
    for (int off = 32; off; off >>= 1) den += __shfl_xor(den, off);
    a0 += __shfl_xor(a0, 16); a0 += __shfl_xor(a0, 32);
    a1 += __shfl_xor(a1, 16); a1 += __shfl_xor(a1, 32);
    a2 += __shfl_xor(a2, 16); a2 += __shfl_xor(a2, 32);
    a3 += __shfl_xor(a3, 16); a3 += __shfl_xor(a3, 32);
    a4 += __shfl_xor(a4, 16); a4 += __shfl_xor(a4, 32);
    a5 += __shfl_xor(a5, 16); a5 += __shfl_xor(a5, 32);
    a6 += __shfl_xor(a6, 16); a6 += __shfl_xor(a6, 32);
    a7 += __shfl_xor(a7, 16); a7 += __shfl_xor(a7, 32);
    if (lane < 16) {
        float inv = 1.f / fmaxf(den, 1e-16f);
        float4 b0v = *(const float4*)&bias[ql * 8];
        float4 b1v = *(const float4*)&bias[ql * 8 + 4];
        float r0 = fmaxf(a0 * inv + b0v.x, 0.f);
        float r1 = fmaxf(a1 * inv + b0v.y, 0.f);
        float r2 = fmaxf(a2 * inv + b0v.z, 0.f);
        float r3 = fmaxf(a3 * inv + b0v.w, 0.f);
        float r4 = fmaxf(a4 * inv + b1v.x, 0.f);
        float r5 = fmaxf(a5 * inv + b1v.y, 0.f);
        float r6 = fmaxf(a6 * inv + b1v.z, 0.f);
        float r7 = fmaxf(a7 * inv + b1v.w, 0.f);
        *(uint4*)&actb[(size_t)node * HID + ql * 8] =
            make_uint4(pk2(r0, r1), pk2(r2, r3), pk2(r4, r5), pk2(r6, r7));
    }
}

// ---------------- Layer 1 GEMM: h1(bf16) = act(bf16) @ W1^T, fused alpha dots --
__global__ __launch_bounds__(128) void k_gemm1(
    const unsigned short* __restrict__ actb, const float* __restrict__ W1,
    const float* __restrict__ a_s, const float* __restrict__ a_d,
    unsigned short* __restrict__ h1b, float* __restrict__ as1, float* __restrict__ ad1) {
    __shared__ float w1l[NCLS * HID];
    __shared__ float av[NCLS], adv[NCLS];
    int t = threadIdx.x;
    #pragma unroll
    for (int i = 0; i < 10; ++i) {
        int j = t + 128 * i;
        ((float4*)w1l)[j] = ((const float4*)W1)[j];
    }
    if (t < NCLS) { av[t] = a_s[t]; adv[t] = a_d[t]; }
    __syncthreads();
    int n = blockIdx.x * 128 + t;
    if (n >= N_NODES) return;
    const uint4* ar = (const uint4*)(actb + (size_t)n * HID);   // 8 bf16 per uint4
    float acc[NCLS];
    #pragma unroll
    for (int c = 0; c < NCLS; ++c) acc[c] = 0.f;
    for (int k0 = 0; k0 < HID; k0 += 8) {
        uint4 v = ar[k0 >> 3];
        float x0 = blo(v.x), x1 = bhi(v.x), x2 = blo(v.y), x3 = bhi(v.y);
        float x4 = blo(v.z), x5 = bhi(v.z), x6 = blo(v.w), x7 = bhi(v.w);
        #pragma unroll
        for (int c = 0; c < NCLS; ++c) {
            const float* wr = &w1l[c * HID + k0];
            acc[c] += x0 * wr[0] + x1 * wr[1] + x2 * wr[2] + x3 * wr[3]
                    + x4 * wr[4] + x5 * wr[5] + x6 * wr[6] + x7 * wr[7];
        }
    }
    float ps = 0.f, pd = 0.f;
    #pragma unroll
    for (int c = 0; c < NCLS; ++c) { ps += acc[c] * av[c]; pd += acc[c] * adv[c]; }
    unsigned pk_[20];
    #pragma unroll
    for (int c = 0; c < 20; ++c) pk_[c] = pk2(acc[2 * c], acc[2 * c + 1]);
    #pragma unroll
    for (int i = 0; i < 5; ++i)
        *(uint4*)&h1b[(size_t)n * NCLS + i * 8] = make_uint4(pk_[4*i], pk_[4*i+1], pk_[4*i+2], pk_[4*i+3]);
    as1[n] = ps; ad1[n] = pd;
}

// ---------------- Aggregation layer 1 (bf16 h1, C=40): quarter-wave uint2 ------
__global__ __launch_bounds__(256) void k_agg1(
    const uint2* __restrict__ h1u, const float* __restrict__ as, const float* __restrict__ ad,
    const int* __restrict__ rp, const int* __restrict__ csr,
    const float* __restrict__ bias, float* __restrict__ out) {
    __shared__ float sw_[4][64];
    __shared__ int   ss_[4][64];
    int wid = threadIdx.x >> 6, lane = threadIdx.x & 63;
    int q = lane >> 4, ql = lane & 15;
    int off10 = (ql < 10) ? ql : 0;   // lanes 10-15 of each group read col 0 (discarded)
    int node = blockIdx.x * 4 + wid;
    int start = rp[node], end = rp[node + 1];
    float ad_n = ad[node];
    float a0 = 0.f, a1 = 0.f, a2 = 0.f, a3 = 0.f, den = 0.f;
    for (int base = start; base < end; base += 64) {
        int mm = end - base; if (mm > 64) mm = 64;
        int s_l = 0; float w_l = 0.f;
        if (lane < mm) {
            s_l = csr[base + lane];
            float e = as[s_l] + ad_n;
            e = (e > 0.f) ? e : NEG * e;
            w_l = __expf(e);
            den += w_l;
        }
        ss_[wid][lane] = s_l;
        sw_[wid][lane] = w_l;
        for (int jj = 0; jj < mm; jj += 16) {
            int i0 = jj + q, i1 = i0 + 4, i2 = i0 + 8, i3 = i0 + 12;
            int   s0 = ss_[wid][i0], s1 = ss_[wid][i1], s2 = ss_[wid][i2], s3 = ss_[wid][i3];
            float w0 = sw_[wid][i0], w1 = sw_[wid][i1], w2 = sw_[wid][i2], w3 = sw_[wid][i3];
            uint2 u0 = h1u[(size_t)s0 * 10 + off10];
            uint2 u1 = h1u[(size_t)s1 * 10 + off10];
            uint2 u2 = h1u[(size_t)s2 * 10 + off10];
            uint2 u3 = h1u[(size_t)s3 * 10 + off10];
            a0 += w0 * blo(u0.x) + w1 * blo(u1.x) + w2 * blo(u2.x) + w3 * blo(u3.x);
            a1 += w0 * bhi(u0.x) + w1 * bhi(u1.x) + w2 * bhi(u2.x) + w3 * bhi(u3.x);
            a2 += w0 * blo(u0.y) + w1 * blo(u1.y) + w2 * blo(u2.y) + w3 * blo(u3.y);
            a3 += w0 * bhi(u0.y) + w1 * bhi(u1.y) + w2 * bhi(u2.y) + w3 * bhi(u3.y);
        }
    }
    #pragma unroll
    for (int off = 32; off; off >>= 1) den += __shfl_xor(den, off);
    a0 += __shfl_xor(a0, 16); a0 += __shfl_xor(a0, 32);
    a1 += __shfl_xor(a1, 16); a1 += __shfl_xor(a1, 32);
    a2 += __shfl_xor(a2, 16); a2 += __shfl_xor(a2, 32);
    a3 += __shfl_xor(a3, 16); a3 += __shfl_xor(a3, 32);
    if (lane < 10) {
        float inv = 1.f / fmaxf(den, 1e-16f);
        float4 b4 = *(const float4*)&bias[ql * 4];
        float4 r;
        r.x = a0 * inv + b4.x;
        r.y = a1 * inv + b4.y;
        r.z = a2 * inv + b4.z;
        r.w = a3 * inv + b4.w;
        *(float4*)&out[(size_t)node * NCLS + ql * 4] = r;
    }
}

extern "C" void kernel_launch(void* const* d_in, const int* in_sizes, int n_in,
                              void* d_out, int out_size, void* d_ws, size_t ws_size,
                              hipStream_t stream) {
    const float* x    = (const float*)d_in[0];
    const int*   ei   = (const int*)d_in[1];
    const float* W0   = (const float*)d_in[2];
    const float* a_s0 = (const float*)d_in[3];
    const float* a_d0 = (const float*)d_in[4];
    const float* b0   = (const float*)d_in[5];
    const float* W1   = (const float*)d_in[6];
    const float* a_s1 = (const float*)d_in[7];
    const float* a_d1 = (const float*)d_in[8];
    const float* b1   = (const float*)d_in[9];

    char* p = (char*)d_ws;
    auto alloc = [&](size_t bytes) { void* q = p; p += (bytes + 255) & ~size_t(255); return q; };
    unsigned short* h0b = (unsigned short*)alloc((size_t)N_NODES * HID * 2);   // 12.8MB bf16 (aliases buf)
    unsigned int*   buf = (unsigned int*)h0b;   // 391*5120*4 = 8.0MB: consumed before gemm0 writes h0b
    unsigned short* h1b = (unsigned short*)alloc(((size_t)N_NODES * NCLS + 32) * 2); // bf16 (+pad)
    unsigned short* actb = (unsigned short*)alloc((size_t)N_NODES * HID * 2);  // bf16
    float* as0    = (float*)alloc((size_t)N_NODES * 4);
    float* ad0    = (float*)alloc((size_t)N_NODES * 4);
    float* as1    = (float*)alloc((size_t)N_NODES * 4);
    float* ad1    = (float*)alloc((size_t)N_NODES * 4);
    int*   rp     = (int*)alloc((size_t)(N_NODES + 1) * 4);
    int*   csr    = (int*)alloc((size_t)ET * 4);
    int*   cstart = (int*)alloc((size_t)(NBUCK + 1) * 4);
    int*   cursor = (int*)alloc((size_t)NBUCK * 4);

    k_init<<<(NBUCK + 255) / 256, 256, 0, stream>>>(cursor);
    k_bin_scatter<<<(ET + CHUNK - 1) / CHUNK, 256, 0, stream>>>(ei, cursor, buf);
    k_bin_scan<<<1, 512, 0, stream>>>(cursor, cstart, rp);
    k_bucket_build<<<NBUCK, 256, 0, stream>>>(buf, cursor, cstart, rp, csr);
    k_gemm0<<<(N_NODES + 63) / 64, 256, 0, stream>>>(x, W0, a_s0, a_d0, h0b, as0, ad0);
    k_agg0<<<N_NODES / 4, 256, 0, stream>>>((const uint4*)h0b, as0, ad0, rp, csr, b0, actb);
    k_gemm1<<<(N_NODES + 127) / 128, 128, 0, stream>>>(actb, W1, a_s1, a_d1, h1b, as1, ad1);
    k_agg1<<<N_NODES / 4, 256, 0, stream>>>((const uint2*)h1b, as1, ad1, rp, csr, b1, (float*)d_out);
}

// Round 12
// 271.268 us; speedup vs baseline: 1.3166x; 1.0485x over previous
//
#include <hip/hip_runtime.h>
#include <hip/hip_bf16.h>

#define N_NODES 50000
#define N_EDGES 1600000
#define ET (N_EDGES + N_NODES)   // self-loops appended
#define IN_DIM 256
#define HID 128
#define NCLS 40
#define NEG 0.2f
#define NBUCK 391                // ceil(50000 / 128) buckets of 128 dst nodes
#define CHUNK 4096               // edges per binning block
#define CAP 5120                 // fixed bucket capacity (mean 4224, sigma ~65)
#define SCATB ((ET + CHUNK - 1) / CHUNK)   // 403 scatter blocks
#define GEMMB ((N_NODES + 63) / 64)        // 782 gemm0 blocks

typedef short bf16x8 __attribute__((ext_vector_type(8)));
typedef float f32x4  __attribute__((ext_vector_type(4)));

__device__ __forceinline__ unsigned pk2(float a, float b) {
    __hip_bfloat16 ha = __float2bfloat16(a), hb = __float2bfloat16(b);
    unsigned short ua = *(unsigned short*)&ha, ub = *(unsigned short*)&hb;
    return (unsigned)ua | ((unsigned)ub << 16);
}
__device__ __forceinline__ float blo(unsigned u) { return __uint_as_float(u << 16); }
__device__ __forceinline__ float bhi(unsigned u) { return __uint_as_float(u & 0xffff0000u); }

__global__ void k_init(int* __restrict__ cursor) {
    int i = blockIdx.x * 256 + threadIdx.x;
    if (i < NBUCK) cursor[i] = i * CAP;
}

// ---------------- Fused: edge binning (blocks 0..SCATB) ∥ gemm0 (rest) --------
// Scatter is independent of gemm0; dispatch order puts scatter first so it
// hides under gemm0's MFMA work. LDS pool = max(gemm0 27.6KB, scatter 19.5KB).
__global__ __launch_bounds__(256) void k_fused(
    const int* __restrict__ ei, int* __restrict__ cursor, unsigned int* __restrict__ buf,
    const float* __restrict__ x, const float* __restrict__ W0,
    const float* __restrict__ a_s, const float* __restrict__ a_d,
    unsigned short* __restrict__ h0b, float* __restrict__ as0, float* __restrict__ ad0) {
    __shared__ unsigned pool[6912];   // 27.6 KB
    int t = threadIdx.x;

    if (blockIdx.x < SCATB) {
        // ---- edge scatter into fixed-capacity buckets ----
        int* sd    = (int*)pool;            // [4096]
        int* hist  = (int*)pool + 4096;     // [391]
        int* wbase = (int*)pool + 4487;     // [391]
        for (int i = t; i < NBUCK; i += 256) hist[i] = 0;
        __syncthreads();
        int base = blockIdx.x * CHUNK;
        #pragma unroll
        for (int j = 0; j < 16; ++j) {
            int i = base + j * 256 + t;
            int d = -1;
            if (i < ET) d = (i < N_EDGES) ? ei[N_EDGES + i] : (i - N_EDGES);
            sd[j * 256 + t] = d;
            if (d >= 0) atomicAdd(&hist[d >> 7], 1);
        }
        __syncthreads();
        for (int i = t; i < NBUCK; i += 256) {
            int h = hist[i];
            wbase[i] = h ? atomicAdd(&cursor[i], h) : 0;
            hist[i] = 0;              // reuse as running offset
        }
        __syncthreads();
        #pragma unroll
        for (int j = 0; j < 16; ++j) {
            int i = base + j * 256 + t;
            int d = sd[j * 256 + t];
            if (d >= 0) {
                int s_ = (i < N_EDGES) ? ei[i] : d;
                int b = d >> 7;
                int off = atomicAdd(&hist[b], 1);
                buf[wbase[b] + off] = ((unsigned)(d & 127) << 16) | (unsigned)s_;
            }
        }
        return;
    }

    // ---- gemm0: MFMA bf16, h0(bf16) = x @ W0^T + fused alpha dots ----
    unsigned* sA = pool;              // bf16 [64 rows][72]  (2304 dwords)
    unsigned* sB = pool + 2304;       // bf16 [128 cols][72] (4608 dwords)
    int n0 = (blockIdx.x - SCATB) * 64;
    int w = t >> 6, lane = t & 63;
    int rw = lane & 15, q = lane >> 4;
    f32x4 acc[8];
    #pragma unroll
    for (int n = 0; n < 8; ++n) acc[n] = (f32x4){0.f, 0.f, 0.f, 0.f};

    for (int kc = 0; kc < IN_DIM; kc += 64) {
        #pragma unroll
        for (int i = 0; i < 4; ++i) {
            int f = i * 256 + t;
            int r = f >> 4, fq = f & 15;
            float4 v = make_float4(0.f, 0.f, 0.f, 0.f);
            if (n0 + r < N_NODES)
                v = *(const float4*)&x[(size_t)(n0 + r) * IN_DIM + kc + fq * 4];
            *(uint2*)&sA[r * 36 + fq * 2] = make_uint2(pk2(v.x, v.y), pk2(v.z, v.w));
        }
        #pragma unroll
        for (int i = 0; i < 8; ++i) {
            int f = i * 256 + t;
            int c = f >> 4, fq = f & 15;
            float4 v = *(const float4*)&W0[(size_t)c * IN_DIM + kc + fq * 4];
            *(uint2*)&sB[c * 36 + fq * 2] = make_uint2(pk2(v.x, v.y), pk2(v.z, v.w));
        }
        __syncthreads();
        #pragma unroll
        for (int ks = 0; ks < 2; ++ks) {
            bf16x8 af = *(const bf16x8*)((const unsigned short*)sA + (16 * w + rw) * 72 + ks * 32 + q * 8);
            #pragma unroll
            for (int n = 0; n < 8; ++n) {
                bf16x8 bfr = *(const bf16x8*)((const unsigned short*)sB + (n * 16 + rw) * 72 + ks * 32 + q * 8);
                acc[n] = __builtin_amdgcn_mfma_f32_16x16x32_bf16(af, bfr, acc[n], 0, 0, 0);
            }
        }
        __syncthreads();
    }

    float asv[8], adv[8];
    #pragma unroll
    for (int n = 0; n < 8; ++n) { asv[n] = a_s[n * 16 + rw]; adv[n] = a_d[n * 16 + rw]; }
    float ps[4] = {0.f, 0.f, 0.f, 0.f}, pd[4] = {0.f, 0.f, 0.f, 0.f};
    #pragma unroll
    for (int n = 0; n < 8; ++n)
        #pragma unroll
        for (int reg = 0; reg < 4; ++reg) {
            float vv = acc[n][reg];
            ps[reg] += vv * asv[n];
            pd[reg] += vv * adv[n];
        }
    #pragma unroll
    for (int reg = 0; reg < 4; ++reg) {
        int node = n0 + 16 * w + q * 4 + reg;
        if (node < N_NODES) {
            #pragma unroll
            for (int n = 0; n < 8; ++n) {
                __hip_bfloat16 hb = __float2bfloat16(acc[n][reg]);
                h0b[(size_t)node * HID + n * 16 + rw] = *(unsigned short*)&hb;
            }
        }
    }
    #pragma unroll
    for (int reg = 0; reg < 4; ++reg)
        #pragma unroll
        for (int off = 1; off < 16; off <<= 1) {
            ps[reg] += __shfl_xor(ps[reg], off);
            pd[reg] += __shfl_xor(pd[reg], off);
        }
    if (rw == 0) {
        #pragma unroll
        for (int reg = 0; reg < 4; ++reg) {
            int node = n0 + 16 * w + q * 4 + reg;
            if (node < N_NODES) { as0[node] = ps[reg]; ad0[node] = pd[reg]; }
        }
    }
}

// ---------------- Bucket build: per-node CSR within fixed-CAP layout -----------
// No global scan needed: csr lives at bucket-major fixed stride; rp/re absolute.
__global__ __launch_bounds__(256) void k_bucket_build(const unsigned int* __restrict__ buf,
                                                      const int* __restrict__ cursor,
                                                      int* __restrict__ rp, int* __restrict__ re,
                                                      int* __restrict__ csr) {
    __shared__ int cnt[128], rpl[128], cur[128];
    int b = blockIdx.x;
    int t = threadIdx.x;
    int lo = b * CAP, hi = cursor[b];
    if (t < 128) cnt[t] = 0;
    __syncthreads();
    for (int i = lo + t; i < hi; i += 256) atomicAdd(&cnt[buf[i] >> 16], 1);
    __syncthreads();
    if (t == 0) {
        int run = 0;
        #pragma unroll
        for (int l = 0; l < 128; ++l) { rpl[l] = run; run += cnt[l]; }
    }
    __syncthreads();
    if (t < 128) {
        int node = b * 128 + t;
        if (node < N_NODES) { rp[node] = lo + rpl[t]; re[node] = lo + rpl[t] + cnt[t]; }
        cur[t] = 0;
    }
    __syncthreads();
    for (int i = lo + t; i < hi; i += 256) {
        unsigned v = buf[i];
        int dl = v >> 16;
        int off = atomicAdd(&cur[dl], 1);
        csr[lo + rpl[dl] + off] = (int)(v & 0xffffu);
    }
}

// ---------------- Aggregation layer 0 (bf16 h0): wave/node, quarter-wave rows --
__global__ __launch_bounds__(256) void k_agg0(
    const uint4* __restrict__ h0q, const float* __restrict__ as, const float* __restrict__ ad,
    const int* __restrict__ rp, const int* __restrict__ re, const int* __restrict__ csr,
    const float* __restrict__ bias, unsigned short* __restrict__ actb) {
    __shared__ float sw_[4][64];
    __shared__ int   ss_[4][64];
    int wid = threadIdx.x >> 6, lane = threadIdx.x & 63;
    int q = lane >> 4, ql = lane & 15;
    int node = blockIdx.x * 4 + wid;
    int start = rp[node], end = re[node];
    float ad_n = ad[node];
    float a0 = 0.f, a1 = 0.f, a2 = 0.f, a3 = 0.f;
    float a4 = 0.f, a5 = 0.f, a6 = 0.f, a7 = 0.f, den = 0.f;
    for (int base = start; base < end; base += 64) {
        int mm = end - base; if (mm > 64) mm = 64;
        int s_l = 0; float w_l = 0.f;
        if (lane < mm) {
            s_l = csr[base + lane];
            float e = as[s_l] + ad_n;
            e = (e > 0.f) ? e : NEG * e;
            w_l = __expf(e);
            den += w_l;
        }
        ss_[wid][lane] = s_l;      // slots >= mm: s=0, w=0 -> contribute 0
        sw_[wid][lane] = w_l;      // wave-local LDS: no barrier needed
        for (int jj = 0; jj < mm; jj += 16) {
            int i0 = jj + q, i1 = i0 + 4, i2 = i0 + 8, i3 = i0 + 12;
            int   s0 = ss_[wid][i0], s1 = ss_[wid][i1], s2 = ss_[wid][i2], s3 = ss_[wid][i3];
            float w0 = sw_[wid][i0], w1 = sw_[wid][i1], w2 = sw_[wid][i2], w3 = sw_[wid][i3];
            uint4 u0 = h0q[(size_t)s0 * 16 + ql];
            uint4 u1 = h0q[(size_t)s1 * 16 + ql];
            uint4 u2 = h0q[(size_t)s2 * 16 + ql];
            uint4 u3 = h0q[(size_t)s3 * 16 + ql];
            a0 += w0 * blo(u0.x) + w1 * blo(u1.x) + w2 * blo(u2.x) + w3 * blo(u3.x);
            a1 += w0 * bhi(u0.x) + w1 * bhi(u1.x) + w2 * bhi(u2.x) + w3 * bhi(u3.x);
            a2 += w0 * blo(u0.y) + w1 * blo(u1.y) + w2 * blo(u2.y) + w3 * blo(u3.y);
            a3 += w0 * bhi(u0.y) + w1 * bhi(u1.y) + w2 * bhi(u2.y) + w3 * bhi(u3.y);
            a4 += w0 * blo(u0.z) + w1 * blo(u1.z) + w2 * blo(u2.z) + w3 * blo(u3.z);
            a5 += w0 * bhi(u0.z) + w1 * bhi(u1.z) + w2 * bhi(u2.z) + w3 * bhi(u3.z);
            a6 += w0 * blo(u0.w) + w1 * blo(u1.w) + w2 * blo(u2.w) + w3 * blo(u3.w);
            a7 += w0 * bhi(u0.w) + w1 * bhi(u1.w) + w2 * bhi(u2.w) + w3 * bhi(u3.w);
        }
    }
    #pragma unroll
    for (int off = 32; off; off >>= 1) den += __shfl_xor(den, off);
    a0 += __shfl_xor(a0, 16); a0 += __shfl_xor(a0, 32);
    a1 += __shfl_xor(a1, 16); a1 += __shfl_xor(a1, 32);
    a2 += __shfl_xor(a2, 16); a2 += __shfl_xor(a2, 32);
    a3 += __shfl_xor(a3, 16); a3 += __shfl_xor(a3, 32);
    a4 += __shfl_xor(a4, 16); a4 += __shfl_xor(a4, 32);
    a5 += __shfl_xor(a5, 16); a5 += __shfl_xor(a5, 32);
    a6 += __shfl_xor(a6, 16); a6 += __shfl_xor(a6, 32);
    a7 += __shfl_xor(a7, 16); a7 += __shfl_xor(a7, 32);
    if (lane < 16) {
        float inv = 1.f / fmaxf(den, 1e-16f);
        float4 b0v = *(const float4*)&bias[ql * 8];
        float4 b1v = *(const float4*)&bias[ql * 8 + 4];
        float r0 = fmaxf(a0 * inv + b0v.x, 0.f);
        float r1 = fmaxf(a1 * inv + b0v.y, 0.f);
        float r2 = fmaxf(a2 * inv + b0v.z, 0.f);
        float r3 = fmaxf(a3 * inv + b0v.w, 0.f);
        float r4 = fmaxf(a4 * inv + b1v.x, 0.f);
        float r5 = fmaxf(a5 * inv + b1v.y, 0.f);
        float r6 = fmaxf(a6 * inv + b1v.z, 0.f);
        float r7 = fmaxf(a7 * inv + b1v.w, 0.f);
        *(uint4*)&actb[(size_t)node * HID + ql * 8] =
            make_uint4(pk2(r0, r1), pk2(r2, r3), pk2(r4, r5), pk2(r6, r7));
    }
}

// ---------------- Layer 1 GEMM: h1(bf16) = act(bf16) @ W1^T, fused alpha dots --
__global__ __launch_bounds__(128) void k_gemm1(
    const unsigned short* __restrict__ actb, const float* __restrict__ W1,
    const float* __restrict__ a_s, const float* __restrict__ a_d,
    unsigned short* __restrict__ h1b, float* __restrict__ as1, float* __restrict__ ad1) {
    __shared__ float w1l[NCLS * HID];
    __shared__ float av[NCLS], adv[NCLS];
    int t = threadIdx.x;
    #pragma unroll
    for (int i = 0; i < 10; ++i) {
        int j = t + 128 * i;
        ((float4*)w1l)[j] = ((const float4*)W1)[j];
    }
    if (t < NCLS) { av[t] = a_s[t]; adv[t] = a_d[t]; }
    __syncthreads();
    int n = blockIdx.x * 128 + t;
    if (n >= N_NODES) return;
    const uint4* ar = (const uint4*)(actb + (size_t)n * HID);   // 8 bf16 per uint4
    float acc[NCLS];
    #pragma unroll
    for (int c = 0; c < NCLS; ++c) acc[c] = 0.f;
    for (int k0 = 0; k0 < HID; k0 += 8) {
        uint4 v = ar[k0 >> 3];
        float x0 = blo(v.x), x1 = bhi(v.x), x2 = blo(v.y), x3 = bhi(v.y);
        float x4 = blo(v.z), x5 = bhi(v.z), x6 = blo(v.w), x7 = bhi(v.w);
        #pragma unroll
        for (int c = 0; c < NCLS; ++c) {
            const float* wr = &w1l[c * HID + k0];
            acc[c] += x0 * wr[0] + x1 * wr[1] + x2 * wr[2] + x3 * wr[3]
                    + x4 * wr[4] + x5 * wr[5] + x6 * wr[6] + x7 * wr[7];
        }
    }
    float ps = 0.f, pd = 0.f;
    #pragma unroll
    for (int c = 0; c < NCLS; ++c) { ps += acc[c] * av[c]; pd += acc[c] * adv[c]; }
    unsigned pk_[20];
    #pragma unroll
    for (int c = 0; c < 20; ++c) pk_[c] = pk2(acc[2 * c], acc[2 * c + 1]);
    #pragma unroll
    for (int i = 0; i < 5; ++i)
        *(uint4*)&h1b[(size_t)n * NCLS + i * 8] = make_uint4(pk_[4*i], pk_[4*i+1], pk_[4*i+2], pk_[4*i+3]);
    as1[n] = ps; ad1[n] = pd;
}

// ---------------- Aggregation layer 1 (bf16 h1, C=40): quarter-wave uint2 ------
__global__ __launch_bounds__(256) void k_agg1(
    const uint2* __restrict__ h1u, const float* __restrict__ as, const float* __restrict__ ad,
    const int* __restrict__ rp, const int* __restrict__ re, const int* __restrict__ csr,
    const float* __restrict__ bias, float* __restrict__ out) {
    __shared__ float sw_[4][64];
    __shared__ int   ss_[4][64];
    int wid = threadIdx.x >> 6, lane = threadIdx.x & 63;
    int q = lane >> 4, ql = lane & 15;
    int off10 = (ql < 10) ? ql : 0;   // lanes 10-15 of each group read col 0 (discarded)
    int node = blockIdx.x * 4 + wid;
    int start = rp[node], end = re[node];
    float ad_n = ad[node];
    float a0 = 0.f, a1 = 0.f, a2 = 0.f, a3 = 0.f, den = 0.f;
    for (int base = start; base < end; base += 64) {
        int mm = end - base; if (mm > 64) mm = 64;
        int s_l = 0; float w_l = 0.f;
        if (lane < mm) {
            s_l = csr[base + lane];
            float e = as[s_l] + ad_n;
            e = (e > 0.f) ? e : NEG * e;
            w_l = __expf(e);
            den += w_l;
        }
        ss_[wid][lane] = s_l;
        sw_[wid][lane] = w_l;
        for (int jj = 0; jj < mm; jj += 16) {
            int i0 = jj + q, i1 = i0 + 4, i2 = i0 + 8, i3 = i0 + 12;
            int   s0 = ss_[wid][i0], s1 = ss_[wid][i1], s2 = ss_[wid][i2], s3 = ss_[wid][i3];
            float w0 = sw_[wid][i0], w1 = sw_[wid][i1], w2 = sw_[wid][i2], w3 = sw_[wid][i3];
            uint2 u0 = h1u[(size_t)s0 * 10 + off10];
            uint2 u1 = h1u[(size_t)s1 * 10 + off10];
            uint2 u2 = h1u[(size_t)s2 * 10 + off10];
            uint2 u3 = h1u[(size_t)s3 * 10 + off10];
            a0 += w0 * blo(u0.x) + w1 * blo(u1.x) + w2 * blo(u2.x) + w3 * blo(u3.x);
            a1 += w0 * bhi(u0.x) + w1 * bhi(u1.x) + w2 * bhi(u2.x) + w3 * bhi(u3.x);
            a2 += w0 * blo(u0.y) + w1 * blo(u1.y) + w2 * blo(u2.y) + w3 * blo(u3.y);
            a3 += w0 * bhi(u0.y) + w1 * bhi(u1.y) + w2 * bhi(u2.y) + w3 * bhi(u3.y);
        }
    }
    #pragma unroll
    for (int off = 32; off; off >>= 1) den += __shfl_xor(den, off);
    a0 += __shfl_xor(a0, 16); a0 += __shfl_xor(a0, 32);
    a1 += __shfl_xor(a1, 16); a1 += __shfl_xor(a1, 32);
    a2 += __shfl_xor(a2, 16); a2 += __shfl_xor(a2, 32);
    a3 += __shfl_xor(a3, 16); a3 += __shfl_xor(a3, 32);
    if (lane < 10) {
        float inv = 1.f / fmaxf(den, 1e-16f);
        float4 b4 = *(const float4*)&bias[ql * 4];
        float4 r;
        r.x = a0 * inv + b4.x;
        r.y = a1 * inv + b4.y;
        r.z = a2 * inv + b4.z;
        r.w = a3 * inv + b4.w;
        *(float4*)&out[(size_t)node * NCLS + ql * 4] = r;
    }
}

extern "C" void kernel_launch(void* const* d_in, const int* in_sizes, int n_in,
                              void* d_out, int out_size, void* d_ws, size_t ws_size,
                              hipStream_t stream) {
    const float* x    = (const float*)d_in[0];
    const int*   ei   = (const int*)d_in[1];
    const float* W0   = (const float*)d_in[2];
    const float* a_s0 = (const float*)d_in[3];
    const float* a_d0 = (const float*)d_in[4];
    const float* b0   = (const float*)d_in[5];
    const float* W1   = (const float*)d_in[6];
    const float* a_s1 = (const float*)d_in[7];
    const float* a_d1 = (const float*)d_in[8];
    const float* b1   = (const float*)d_in[9];

    char* p = (char*)d_ws;
    auto alloc = [&](size_t bytes) { void* q = p; p += (bytes + 255) & ~size_t(255); return q; };
    unsigned short* h0b  = (unsigned short*)alloc((size_t)N_NODES * HID * 2);  // 12.8MB bf16
    unsigned int*   buf  = (unsigned int*)alloc((size_t)NBUCK * CAP * 4);      // 8.0MB (NO aliasing: gemm0 runs concurrently)
    int*   csr    = (int*)alloc((size_t)NBUCK * CAP * 4);                      // 8.0MB bucket-major
    unsigned short* h1b  = (unsigned short*)alloc(((size_t)N_NODES * NCLS + 32) * 2);
    unsigned short* actb = (unsigned short*)alloc((size_t)N_NODES * HID * 2);  // bf16
    float* as0    = (float*)alloc((size_t)N_NODES * 4);
    float* ad0    = (float*)alloc((size_t)N_NODES * 4);
    float* as1    = (float*)alloc((size_t)N_NODES * 4);
    float* ad1    = (float*)alloc((size_t)N_NODES * 4);
    int*   rp     = (int*)alloc((size_t)N_NODES * 4);
    int*   re     = (int*)alloc((size_t)N_NODES * 4);
    int*   cursor = (int*)alloc((size_t)NBUCK * 4);

    k_init<<<(NBUCK + 255) / 256, 256, 0, stream>>>(cursor);
    k_fused<<<SCATB + GEMMB, 256, 0, stream>>>(ei, cursor, buf, x, W0, a_s0, a_d0, h0b, as0, ad0);
    k_bucket_build<<<NBUCK, 256, 0, stream>>>(buf, cursor, rp, re, csr);
    k_agg0<<<N_NODES / 4, 256, 0, stream>>>((const uint4*)h0b, as0, ad0, rp, re, csr, b0, actb);
    k_gemm1<<<(N_NODES + 127) / 128, 128, 0, stream>>>(actb, W1, a_s1, a_d1, h1b, as1, ad1);
    k_agg1<<<N_NODES / 4, 256, 0, stream>>>((const uint2*)h1b, as1, ad1, rp, re, csr, b1, (float*)d_out);
}